// Round 10
// baseline (211.414 us; speedup 1.0000x reference)
//
#include <hip/hip_runtime.h>
#include <hip/hip_bf16.h>

#define NN   8192
#define DIN  512
#define DOUT 256

typedef __attribute__((ext_vector_type(8)))  short s16x8;   // 8 bf16 (A/B frag)
typedef __attribute__((ext_vector_type(16))) float f32x16;  // 32x32 C/D frag

static __device__ __forceinline__ unsigned short f2bf(float f) {
    union { float f; unsigned u; } v; v.f = f;
    unsigned r = v.u + 0x7fffu + ((v.u >> 16) & 1u);   // RNE
    return (unsigned short)(r >> 16);
}

static __device__ __forceinline__ void gload_lds16(const void* g, void* l) {
    __builtin_amdgcn_global_load_lds(
        (const __attribute__((address_space(1))) unsigned int*)g,
        (__attribute__((address_space(3))) unsigned int*)l, 16, 0, 0);
}

// ---------------- Kernel 1: Wh = feat@W (fp32 regs) -> WhT bf16, src/dst fused -------
__global__ __launch_bounds__(256) void k_wh2(const float* __restrict__ feat,
                                             const float* __restrict__ W,
                                             const float* __restrict__ a,
                                             unsigned short* __restrict__ WhT,
                                             float* __restrict__ src,
                                             float* __restrict__ dst) {
    __shared__ float lf[16 * DIN];                 // 32 KB
    __shared__ float red[2][4][16];
    const int tid = threadIdx.x;
    const int i0  = blockIdx.x * 16;
    const int w   = tid >> 6, lane = tid & 63;

    const float4* fsrc = (const float4*)(feat + (size_t)i0 * DIN);
    float4* fdst = (float4*)lf;
    #pragma unroll
    for (int q = 0; q < 8; ++q) fdst[tid + q * 256] = fsrc[tid + q * 256];
    __syncthreads();

    const int c = tid;
    float outs[16];
    #pragma unroll
    for (int r = 0; r < 16; ++r) outs[r] = 0.f;

    for (int k = 0; k < DIN; k += 4) {
        float w0 = W[(k + 0) * DOUT + c];
        float w1 = W[(k + 1) * DOUT + c];
        float w2 = W[(k + 2) * DOUT + c];
        float w3 = W[(k + 3) * DOUT + c];
        #pragma unroll
        for (int r = 0; r < 16; ++r) {
            float4 f = *(const float4*)&lf[r * DIN + k];   // broadcast read
            outs[r] = fmaf(f.x, w0, fmaf(f.y, w1, fmaf(f.z, w2, fmaf(f.w, w3, outs[r]))));
        }
    }

    unsigned short tb[16];
    #pragma unroll
    for (int r = 0; r < 16; ++r) tb[r] = f2bf(outs[r]);
    uint4* wt = (uint4*)(WhT + (size_t)c * NN + i0);
    wt[0] = *(uint4*)&tb[0];
    wt[1] = *(uint4*)&tb[8];

    const float as_ = a[c], ad_ = a[DOUT + c];
    #pragma unroll
    for (int r = 0; r < 16; ++r) {
        float s = outs[r] * as_;
        float d = outs[r] * ad_;
        #pragma unroll
        for (int off = 32; off; off >>= 1) {
            s += __shfl_xor(s, off);
            d += __shfl_xor(d, off);
        }
        if (lane == 0) { red[0][w][r] = s; red[1][w][r] = d; }
    }
    __syncthreads();
    if (tid < 16)
        src[i0 + tid] = red[0][0][tid] + red[0][1][tid] + red[0][2][tid] + red[0][3][tid];
    else if (tid < 32) {
        int r = tid - 16;
        dst[i0 + r] = red[1][0][r] + red[1][1][r] + red[1][2][r] + red[1][3][r];
    }
}

// ---------------- Kernel 1b: adj -> bitmask, LINEAR layout ---------------------------
// bits byte b of row = cols [b*8, b*8+8); bit jj = (adj[row][b*8+jj] > 0).
__global__ __launch_bounds__(256) void k_mask(const int* __restrict__ adj,
                                              unsigned char* __restrict__ bits) {
    const int row = blockIdx.x;
    const int tid = threadIdx.x;
    const int* base = adj + (size_t)row * NN + tid * 32;
    unsigned int u = 0;
    #pragma unroll
    for (int j = 0; j < 8; ++j) {
        int4 v = *(const int4*)(base + j * 4);
        unsigned int b = (v.x > 0 ? 1u : 0u) | (v.y > 0 ? 2u : 0u) |
                         (v.z > 0 ? 4u : 0u) | (v.w > 0 ? 8u : 0u);
        u |= b << (j * 4);
    }
    *(unsigned int*)(bits + (size_t)row * 1024 + tid * 4) = u;
}

// ---------------- Kernel 2: masked-exp GEMM, P ENTIRELY IN REGISTERS -----------------
// grid = 512: ks = bid&7 (k-split 8, XCD-pinned -> WhT slice 512 KB + bits 1 MB per
// XCD L2), rt = bid>>3 (64 row tiles of 128). block = 256 thr = 4 waves.
// Wave = 32 rows x 256 cols: lane builds P[row=l&31][k=(l>>5)*8+j] per ks4 -- exactly
// the 32x32x16 A-fragment layout -> NO P LDS, NO cross-wave A dependency. P built
// exactly once chip-wide. B: dbuf LDS slab [256 col][64 k], 1 barrier/step; drain
// covers a full step (~2000 cy > L3 latency). acc 8 col-tiles x 16 = 128 VGPR.
#define STEP9(T, PA, PB)                                                                 \
{                                                                                        \
    /* stage B(T+1) -> Bs[(T+1)&1] (clamped restage at T=15: harmless) */                \
    {                                                                                    \
        const size_t koff_ = (size_t)(((T) + 1 <= 15) ? (T) + 1 : 15) * 128;             \
        _Pragma("unroll")                                                                \
        for (int q = 0; q < 8; ++q)                                                      \
            gload_lds16(gB + (size_t)q * (32 * NN * 2) + koff_,                          \
                        Bs[((T) + 1) & 1] + q * 4096 + tid * 16);                        \
    }                                                                                    \
    /* issue P(T+1) inputs early (L1/L2-hot) */                                          \
    unsigned long long m64_ = 0;                                                         \
    float4 dv_[8];                                                                       \
    if ((T) < 15) {                                                                      \
        m64_ = brow64[(T) + 1];                                                          \
        _Pragma("unroll")                                                                \
        for (int ks4 = 0; ks4 < 4; ++ks4) {                                              \
            dv_[2 * ks4]     = *(const float4*)(dstk + ((T) + 1) * 64 + ks4 * 16 + lhi8);\
            dv_[2 * ks4 + 1] = *(const float4*)(dstk + ((T) + 1) * 64 + ks4 * 16 + lhi8 + 4);\
        }                                                                                \
    }                                                                                    \
    /* MFMA(T): A = PA regs, B = Bs[T&1] */                                              \
    __builtin_amdgcn_s_setprio(1);                                                       \
    _Pragma("unroll")                                                                    \
    for (int ks4 = 0; ks4 < 4; ++ks4) {                                                  \
        _Pragma("unroll")                                                                \
        for (int ct = 0; ct < 8; ++ct) {                                                 \
            const int brow_ = ct * 32 + l31;                                             \
            s16x8 bfv_ = *(const s16x8*)(Bs[(T) & 1] + brow_ * 128 +                     \
                                         ((ks4 * 32 + lhi * 16) ^ ((brow_ & 7) << 4)));  \
            acc[ct] = __builtin_amdgcn_mfma_f32_32x32x16_bf16(PA[ks4], bfv_, acc[ct], 0, 0, 0); \
        }                                                                                \
    }                                                                                    \
    __builtin_amdgcn_s_setprio(0);                                                       \
    /* build P(T+1) -> PB (pure VALU; overlaps MFMA pipe) */                             \
    if ((T) < 15) {                                                                      \
        const float* df_ = (const float*)dv_;                                            \
        _Pragma("unroll")                                                                \
        for (int ks4 = 0; ks4 < 4; ++ks4) {                                              \
            const unsigned int m8_ = (unsigned int)(m64_ >> (ks4 * 16 + lhi8)) & 0xffu;  \
            s16x8 pw_;                                                                   \
            _Pragma("unroll")                                                            \
            for (int jj = 0; jj < 8; ++jj) {                                             \
                float x_ = si + df_[ks4 * 8 + jj];                                       \
                x_ = fmaxf(x_, 0.2f * x_);                  /* leaky_relu 0.2 */         \
                float p_ = (m8_ >> jj) & 1u ? __expf(x_) : 0.f;  /* bounded logits */    \
                den += p_;                                                               \
                pw_[jj] = (short)f2bf(p_);                                               \
            }                                                                            \
            PB[ks4] = pw_;                                                               \
        }                                                                                \
    }                                                                                    \
    asm volatile("s_waitcnt vmcnt(0) lgkmcnt(0)" ::: "memory");                          \
    __builtin_amdgcn_s_barrier();                                                        \
    __builtin_amdgcn_sched_barrier(0);                                                   \
}

__global__ __launch_bounds__(256, 2) void k_attn9(const unsigned char* __restrict__ bits,
                                                  const unsigned short* __restrict__ WhT,
                                                  const float* __restrict__ src,
                                                  const float* __restrict__ dstg,
                                                  float* __restrict__ denp,
                                                  float* __restrict__ part) {
    __shared__ __attribute__((aligned(16))) char Bs[2][32768];  // [256 col][64 k] swz dbuf

    const int tid  = threadIdx.x;
    const int lane = tid & 63;
    const int wv   = tid >> 6;                     // wave 0..3 -> rows wv*32..+32
    const int l31  = lane & 31, lhi = lane >> 5;
    const int lhi8 = lhi * 8;

    const int ks  = blockIdx.x & 7;                // k-split (XCD-pinned)
    const int rt  = blockIdx.x >> 3;               // 0..63
    const int kb0 = ks * 1024;

    const int gr  = rt * 128 + wv * 32 + l31;      // this lane's P row
    const float si = src[gr];
    const unsigned long long* brow64 =
        (const unsigned long long*)(bits + (size_t)gr * 1024 + ks * 128);
    const float* dstk = dstg + kb0;

    // B staging base: thread covers cols {q*32 + c0}, slot tid&7 (same swizzle all q)
    const int c0 = tid >> 3;
    const char* gB = (const char*)WhT + ((size_t)c0 * NN + kb0) * 2
                   + (((tid & 7) * 16) ^ ((c0 & 7) << 4));

    f32x16 acc[8];
    #pragma unroll
    for (int ct = 0; ct < 8; ++ct)
        #pragma unroll
        for (int e = 0; e < 16; ++e) acc[ct][e] = 0.f;
    float den = 0.f;

    s16x8 pA[4], pB[4];

    // prologue: stage B(0) -> Bs[0]; build P(0) -> pA
    #pragma unroll
    for (int q = 0; q < 8; ++q)
        gload_lds16(gB + (size_t)q * (32 * NN * 2), Bs[0] + q * 4096 + tid * 16);
    {
        const unsigned long long m64 = brow64[0];
        #pragma unroll
        for (int ks4 = 0; ks4 < 4; ++ks4) {
            float4 d0 = *(const float4*)(dstk + ks4 * 16 + lhi8);
            float4 d1 = *(const float4*)(dstk + ks4 * 16 + lhi8 + 4);
            const float df[8] = {d0.x, d0.y, d0.z, d0.w, d1.x, d1.y, d1.z, d1.w};
            const unsigned int m8 = (unsigned int)(m64 >> (ks4 * 16 + lhi8)) & 0xffu;
            s16x8 pw;
            #pragma unroll
            for (int jj = 0; jj < 8; ++jj) {
                float x = si + df[jj];
                x = fmaxf(x, 0.2f * x);
                float p = (m8 >> jj) & 1u ? __expf(x) : 0.f;
                den += p;
                pw[jj] = (short)f2bf(p);
            }
            pA[ks4] = pw;
        }
    }
    asm volatile("s_waitcnt vmcnt(0) lgkmcnt(0)" ::: "memory");
    __builtin_amdgcn_s_barrier();
    __builtin_amdgcn_sched_barrier(0);

    #pragma unroll
    for (int tt = 0; tt < 8; ++tt) {
        STEP9(2 * tt,     pA, pB);
        STEP9(2 * tt + 1, pB, pA);
    }

    // den: combine lhi halves (lane ^ 32), lanes 0-31 hold full row partials
    den += __shfl_xor(den, 32);
    if (lhi == 0) denp[(size_t)ks * NN + gr] = den;

    // epilogue: C/D layout (m74/m101): col = lane&31, row = (e&3)+8*(e>>2)+4*lhi
    float* pp = part + (size_t)ks * (NN * DOUT);
    #pragma unroll
    for (int ct = 0; ct < 8; ++ct) {
        #pragma unroll
        for (int e = 0; e < 16; ++e) {
            const int row = rt * 128 + wv * 32 + (e & 3) + 8 * (e >> 2) + 4 * lhi;
            pp[(size_t)row * DOUT + ct * 32 + l31] = acc[ct][e];
        }
    }
}

// ---------------- Kernel 3: out = elu( (sum_ks num) / (sum_ks den) ) -----------------
__global__ __launch_bounds__(256) void k_finish3(const float* __restrict__ part,
                                                 const float* __restrict__ denp,
                                                 float* __restrict__ out) {
    const int idx = blockIdx.x * 256 + threadIdx.x;   // float4 units
    const int row = idx >> 6;                          // 64 float4 per row
    float den = 0.f;
    #pragma unroll
    for (int i = 0; i < 8; ++i) den += denp[(size_t)i * NN + row];
    float rv = den > 0.f ? 1.f / den : 0.f;
    const size_t st = (size_t)NN * DOUT / 4;
    const float4* p = (const float4*)part;
    float sx = 0.f, sy = 0.f, sz = 0.f, sw = 0.f;
    #pragma unroll
    for (int i = 0; i < 8; ++i) {
        float4 v = p[idx + i * st];
        sx += v.x; sy += v.y; sz += v.z; sw += v.w;
    }
    float4 s;
    s.x = sx * rv; s.y = sy * rv; s.z = sz * rv; s.w = sw * rv;
    s.x = s.x > 0.f ? s.x : expm1f(s.x);
    s.y = s.y > 0.f ? s.y : expm1f(s.y);
    s.z = s.z > 0.f ? s.z : expm1f(s.z);
    s.w = s.w > 0.f ? s.w : expm1f(s.w);
    ((float4*)out)[idx] = s;
}

extern "C" void kernel_launch(void* const* d_in, const int* in_sizes, int n_in,
                              void* d_out, int out_size, void* d_ws, size_t ws_size,
                              hipStream_t stream) {
    const float* feat = (const float*)d_in[0];
    const int*   adj  = (const int*)d_in[1];
    const float* W    = (const float*)d_in[2];
    const float* a    = (const float*)d_in[3];
    float* out = (float*)d_out;

    char* ws = (char*)d_ws;
    unsigned short* WhT  = (unsigned short*)ws;               // 4 MB
    float*          src  = (float*)(ws + 4194304);            // 32 KB
    float*          dst  = (float*)(ws + 4227072);            // 32 KB
    float*          denp = (float*)(ws + 4259840);            // 256 KB (8 x 32 KB)
    unsigned char*  bits = (unsigned char*)(ws + 4521984);    // 8 MB
    float*          part = (float*)(ws + 12910592);           // 64 MB (8 x 8 MB)

    k_mask   <<<8192, 256, 0, stream>>>(adj, bits);
    k_wh2    <<<512,  256, 0, stream>>>(feat, W, a, WhT, src, dst);
    k_attn9  <<<512,  256, 0, stream>>>(bits, WhT, src, dst, denp, part);
    k_finish3<<<2048, 256, 0, stream>>>(part, denp, out);
}